// Round 19
// baseline (167.200 us; speedup 1.0000x reference)
//
#include <hip/hip_runtime.h>
#include <math.h>

#define HH 256
#define WW 256
#define NN (HH * WW)

typedef _Float16 f16;
typedef _Float16 f16x4 __attribute__((ext_vector_type(4)));
typedef _Float16 f16x8 __attribute__((ext_vector_type(8)));
typedef float f32x4 __attribute__((ext_vector_type(4)));

#define OQ 75264  // qkv B-frag base inside BF (f16 units)
#define CS 56     // conv LDS slot stride in f16 (R14/R18 proven)
#define IS 40     // im2col row stride in f16

__device__ inline float dot8p(f16x8 a, f16x8 b, float acc) {
#if __has_builtin(__builtin_amdgcn_fdot2)
  acc = __builtin_amdgcn_fdot2(__builtin_shufflevector(a, a, 0, 1),
                               __builtin_shufflevector(b, b, 0, 1), acc, false);
  acc = __builtin_amdgcn_fdot2(__builtin_shufflevector(a, a, 2, 3),
                               __builtin_shufflevector(b, b, 2, 3), acc, false);
  acc = __builtin_amdgcn_fdot2(__builtin_shufflevector(a, a, 4, 5),
                               __builtin_shufflevector(b, b, 4, 5), acc, false);
  acc = __builtin_amdgcn_fdot2(__builtin_shufflevector(a, a, 6, 7),
                               __builtin_shufflevector(b, b, 6, 7), acc, false);
  return acc;
#else
#pragma unroll
  for (int i = 0; i < 8; ++i) acc += (float)a[i] * (float)b[i];
  return acc;
#endif
}

// ---------------------------------------------------------------------------
// Weight repack element e -> BF[e] (unchanged, proven).
// ---------------------------------------------------------------------------
__device__ __forceinline__ float repack_elem(
    int e, const float* __restrict__ w0, const float* __restrict__ w1,
    const float* __restrict__ w2, const float* __restrict__ w3,
    const float* __restrict__ qw, const float* __restrict__ kw,
    const float* __restrict__ vw) {
  const int O1 = 1536, O2 = O1 + 27648, O3 = O2 + 27648;
  float val = 0.f;
  if (e >= OQ) {
    int idx = e - OQ;
    int mat = idx >> 10;
    int r = idx & 1023;
    int nt = r >> 9;
    int ln = (r >> 3) & 63;
    int j = r & 7;
    int nn = ln & 15, qd = ln >> 4;
    int ci = qd * 8 + j, co = nt * 16 + nn;
    const float* w = (mat == 0) ? qw : (mat == 1) ? kw : vw;
    if (ci < 24 && co < 24) val = w[co * 24 + ci];
  } else if (e < O1) {
    int j = e & 7;
    int ln = (e >> 3) & 63;
    int nt = e >> 9;
    int nn = ln & 15, qd = ln >> 4;
    int k = qd * 8 + j;
    int cout = nt * 16 + nn;
    if (k < 27) {
      int tap = k / 3, ci = k - tap * 3;
      val = w0[(cout * 3 + ci) * 9 + tap];
    }
  } else {
    const float* w;
    int COUT, idx;
    if (e < O2)      { w = w1; COUT = 48; idx = e - O1; }
    else if (e < O3) { w = w2; COUT = 48; idx = e - O2; }
    else             { w = w3; COUT = 24; idx = e - O3; }
    const int NT = (COUT == 48) ? 3 : 2;
    int j = idx & 7;
    int ln = (idx >> 3) & 63;
    int rest = idx >> 9;
    int nt = rest % NT;
    int q2 = rest / NT;
    int kc = q2 & 1;
    int tap = q2 >> 1;
    int nn = ln & 15, qd = ln >> 4;
    int ci = kc * 32 + qd * 8 + j;
    int cout = nt * 16 + nn;
    if (ci < 48 && cout < COUT) val = w[(cout * 48 + ci) * 9 + tap];
  }
  return val;
}

__global__ __launch_bounds__(256) void prep(
    const float* __restrict__ w0, const float* __restrict__ w1,
    const float* __restrict__ w2, const float* __restrict__ w3,
    const float* __restrict__ qw, const float* __restrict__ kw,
    const float* __restrict__ vw, f16* __restrict__ bf) {
  int e = blockIdx.x * 256 + threadIdx.x;  // 306*256 = 78336 exactly
  bf[e] = (f16)repack_elem(e, w0, w1, w2, w3, qw, kw, vw);
}

// ---------------------------------------------------------------------------
// Middle conv stage (48->48) — byte-identical to R18 (best measured 51.4 µs).
// ---------------------------------------------------------------------------
template <int W_IN, int W_OUT, int H_OUT, int MAXT>
__device__ __forceinline__ void stage_mid(const f16* __restrict__ inb,
                                          f16* __restrict__ outb,
                                          const f16* __restrict__ bfr,
                                          const float* __restrict__ bias,
                                          int gy0, int gx0, int tid) {
  const int P = W_OUT * H_OUT;
  const int T = (P + 15) >> 4;
  const int lane = tid & 63, wave = tid >> 6;
  const int n = lane & 15, quad = lane >> 4;
  const int cbase = quad * 4;
  f32x4 acc[MAXT][3];
  int ay[MAXT], ax[MAXT];
  float4 bv[3];
#pragma unroll
  for (int nt = 0; nt < 3; ++nt)
    bv[nt] = *(const float4*)(bias + nt * 16 + cbase);
#pragma unroll
  for (int ti = 0; ti < MAXT; ++ti) {
    int qa = (wave + 4 * ti) * 16 + n;
    int qc = (qa > P - 1) ? (P - 1) : qa;
    ay[ti] = qc / W_OUT;
    ax[ti] = qc - ay[ti] * W_OUT;
#pragma unroll
    for (int nt = 0; nt < 3; ++nt)
      acc[ti][nt] = (f32x4){bv[nt].x, bv[nt].y, bv[nt].z, bv[nt].w};
  }
#pragma unroll 1
  for (int tap = 0; tap < 9; ++tap) {
    const int dy = tap / 3, dx = tap - dy * 3;
    f16x8 B[2][3];
#pragma unroll
    for (int kc = 0; kc < 2; ++kc)
#pragma unroll
      for (int nt = 0; nt < 3; ++nt)
        B[kc][nt] =
            *(const f16x8*)(bfr + (((tap * 2 + kc) * 3 + nt) * 64 + lane) * 8);
#pragma unroll
    for (int ti = 0; ti < MAXT; ++ti) {
      if (wave + 4 * ti < T) {
        const f16* ap = inb + ((ay[ti] + dy) * W_IN + ax[ti] + dx) * CS +
                        quad * 8;
        f16x8 a0 = *(const f16x8*)(ap);
        f16x8 a1 = *(const f16x8*)(ap + 32);
#pragma unroll
        for (int nt = 0; nt < 3; ++nt)
          acc[ti][nt] = __builtin_amdgcn_mfma_f32_16x16x32_f16(
              B[0][nt], a0, acc[ti][nt], 0, 0, 0);
#pragma unroll
        for (int nt = 0; nt < 3; ++nt)
          acc[ti][nt] = __builtin_amdgcn_mfma_f32_16x16x32_f16(
              B[1][nt], a1, acc[ti][nt], 0, 0, 0);
      }
    }
  }
#pragma unroll
  for (int ti = 0; ti < MAXT; ++ti) {
    int qa = (wave + 4 * ti) * 16 + n;
    if (wave + 4 * ti < T && qa < P) {
      int gy = gy0 + ay[ti], gx = gx0 + ax[ti];
      bool im = (gy >= 0 && gy < HH && gx >= 0 && gx < WW);
#pragma unroll
      for (int nt = 0; nt < 3; ++nt) {
        f16x4 h;
#pragma unroll
        for (int reg = 0; reg < 4; ++reg)
          h[reg] = (f16)(im ? fmaxf(acc[ti][nt][reg], 0.f) : 0.f);
        *(f16x4*)(outb + qa * CS + nt * 16 + cbase) = h;
      }
    }
  }
}

// ---------------------------------------------------------------------------
// FUSED CONV CHAIN — byte-identical to R18 (best measured: 51.4 µs).
// ---------------------------------------------------------------------------
__global__ __launch_bounds__(256, 2) void fused_conv(
    const float* __restrict__ x, const float* __restrict__ b0,
    const float* __restrict__ b1, const float* __restrict__ b2,
    const float* __restrict__ b3, const float* __restrict__ sw,
    const float* __restrict__ sb, f16* __restrict__ ABh,
    const f16* __restrict__ BF) {
  extern __shared__ char smem[];
  f16* bufA = (f16*)smem;
  f16* bufB = (f16*)(smem + 34496);
  const int tid = threadIdx.x;
  const int bz = blockIdx.x;
  const int z = bz >> 9, tt = bz & 511;
  const int bx = (tt & 15) * 16, by = (tt >> 4) * 8;
  const int lane = tid & 63, wave = tid >> 6;
  const int n = lane & 15, quad = lane >> 4;
  const int cbase = quad * 4;
  const float* xz = x + (size_t)z * 3 * NN;

  f16x8 B0[3];
#pragma unroll
  for (int nt = 0; nt < 3; ++nt)
    B0[nt] = *(const f16x8*)(BF + (nt * 64 + lane) * 8);

  for (int i = tid; i < 3840; i += 256) {  // 61440 B
    f16x8 zz = {};
    *(f16x8*)(smem + i * 16) = zz;
  }
  __syncthreads();

  for (int p = tid; p < 308; p += 256) {
    int py = p / 22, px = p - py * 22;
    int gy = by - 3 + py, gx = bx - 3 + px;
    f16 row[32];
#pragma unroll
    for (int k = 27; k < 32; ++k) row[k] = (f16)0.f;
#pragma unroll
    for (int tap = 0; tap < 9; ++tap) {
      int dy = tap / 3, dx = tap - (tap / 3) * 3;
      int sy = gy + dy - 1, sx = gx + dx - 1;
      f16 c0 = (f16)0.f, c1 = c0, c2 = c0;
      if (sy >= 0 && sy < HH && sx >= 0 && sx < WW) {
        int o = sy * WW + sx;
        c0 = (f16)xz[o];
        c1 = (f16)xz[NN + o];
        c2 = (f16)xz[2 * NN + o];
      }
      row[tap * 3 + 0] = c0;
      row[tap * 3 + 1] = c1;
      row[tap * 3 + 2] = c2;
    }
    f16* dst = bufB + p * IS;
#pragma unroll
    for (int c = 0; c < 4; ++c)
      *(f16x8*)(dst + c * 8) = *(f16x8*)(row + c * 8);
  }
  __syncthreads();

  {
    float4 bv[3];
#pragma unroll
    for (int nt = 0; nt < 3; ++nt)
      bv[nt] = *(const float4*)(b0 + nt * 16 + cbase);
    f32x4 acc[5][3];
    int pya[5], pxa[5];
#pragma unroll
    for (int ti = 0; ti < 5; ++ti) {
      int qa = (wave + 4 * ti) * 16 + n;
      int qc = (qa > 307) ? 307 : qa;
      pya[ti] = qc / 22;
      pxa[ti] = qc - pya[ti] * 22;
#pragma unroll
      for (int nt = 0; nt < 3; ++nt)
        acc[ti][nt] = (f32x4){bv[nt].x, bv[nt].y, bv[nt].z, bv[nt].w};
    }
#pragma unroll
    for (int ti = 0; ti < 5; ++ti) {
      int qa = (wave + 4 * ti) * 16 + n;
      int qc = (qa > 307) ? 307 : qa;
      f16x8 a = *(const f16x8*)(bufB + qc * IS + quad * 8);
#pragma unroll
      for (int nt = 0; nt < 3; ++nt)
        acc[ti][nt] = __builtin_amdgcn_mfma_f32_16x16x32_f16(B0[nt], a,
                                                             acc[ti][nt], 0,
                                                             0, 0);
    }
    __syncthreads();
#pragma unroll
    for (int ti = 0; ti < 5; ++ti) {
      int qa = (wave + 4 * ti) * 16 + n;
      if (qa < 308) {
        int gy = by - 3 + pya[ti], gx = bx - 3 + pxa[ti];
        bool im = (gy >= 0 && gy < HH && gx >= 0 && gx < WW);
#pragma unroll
        for (int nt = 0; nt < 3; ++nt) {
          f16x4 h;
#pragma unroll
          for (int reg = 0; reg < 4; ++reg)
            h[reg] = (f16)(im ? fmaxf(acc[ti][nt][reg], 0.f) : 0.f);
          *(f16x4*)(bufA + qa * CS + nt * 16 + cbase) = h;
        }
      }
    }
  }
  __syncthreads();

  stage_mid<22, 20, 12, 4>(bufA, bufB, BF + 1536, b1, by - 2, bx - 2, tid);
  __syncthreads();
  stage_mid<20, 18, 10, 3>(bufB, bufA, BF + 29184, b2, by - 1, bx - 1, tid);
  __syncthreads();

  {
    f32x4 acc[2][2];
    int ay[2], ax[2];
    float skw0[2][4], skw1[2][4], skw2[2][4], skb4[2][4];
#pragma unroll
    for (int nt = 0; nt < 2; ++nt)
#pragma unroll
      for (int reg = 0; reg < 4; ++reg) {
        int cc = nt * 16 + cbase + reg;
        bool v = (cc < 24);
        skw0[nt][reg] = v ? sw[cc * 3 + 0] : 0.f;
        skw1[nt][reg] = v ? sw[cc * 3 + 1] : 0.f;
        skw2[nt][reg] = v ? sw[cc * 3 + 2] : 0.f;
        skb4[nt][reg] = v ? sb[cc] : 0.f;
      }
#pragma unroll
    for (int ti = 0; ti < 2; ++ti) {
      int qa = (wave + 4 * ti) * 16 + n;
      ay[ti] = qa >> 4;
      ax[ti] = qa & 15;
#pragma unroll
      for (int nt = 0; nt < 2; ++nt) {
        int cc0 = nt * 16 + cbase;
        float4 bv = (cc0 < 24) ? *(const float4*)(b3 + cc0)
                               : make_float4(0.f, 0.f, 0.f, 0.f);
        acc[ti][nt] = (f32x4){bv.x, bv.y, bv.z, bv.w};
      }
    }
#pragma unroll 1
    for (int tap = 0; tap < 9; ++tap) {
      const int dy = tap / 3, dx = tap - dy * 3;
      f16x8 B[2][2];
#pragma unroll
      for (int kc = 0; kc < 2; ++kc)
#pragma unroll
        for (int nt = 0; nt < 2; ++nt)
          B[kc][nt] = *(const f16x8*)(BF + 56832 +
                                      (((tap * 2 + kc) * 2 + nt) * 64 + lane) *
                                          8);
#pragma unroll
      for (int ti = 0; ti < 2; ++ti) {
        const f16* ap = bufA + ((ay[ti] + dy) * 18 + ax[ti] + dx) * CS +
                        quad * 8;
        f16x8 a0 = *(const f16x8*)(ap);
        f16x8 a1 = *(const f16x8*)(ap + 32);
#pragma unroll
        for (int nt = 0; nt < 2; ++nt)
          acc[ti][nt] = __builtin_amdgcn_mfma_f32_16x16x32_f16(
              B[0][nt], a0, acc[ti][nt], 0, 0, 0);
#pragma unroll
        for (int nt = 0; nt < 2; ++nt)
          acc[ti][nt] = __builtin_amdgcn_mfma_f32_16x16x32_f16(
              B[1][nt], a1, acc[ti][nt], 0, 0, 0);
      }
    }
    f16* oz = ABh + (size_t)z * NN * 32;
#pragma unroll
    for (int ti = 0; ti < 2; ++ti) {
      int o = (by + ay[ti]) * WW + bx + ax[ti];
      float xv0 = xz[o], xv1 = xz[NN + o], xv2 = xz[2 * NN + o];
#pragma unroll
      for (int nt = 0; nt < 2; ++nt) {
        int cc0 = nt * 16 + cbase;
        if (cc0 < 24) {
          f16x4 h;
#pragma unroll
          for (int reg = 0; reg < 4; ++reg) {
            float sk = skb4[nt][reg] + skw0[nt][reg] * xv0 +
                       skw1[nt][reg] * xv1 + skw2[nt][reg] * xv2;
            h[reg] = (f16)(fmaxf(acc[ti][nt][reg], 0.f) + sk);
          }
          *(f16x4*)(oz + (size_t)o * 32 + cc0) = h;
        }
      }
    }
#pragma unroll
    for (int ti = 0; ti < 2; ++ti) {
      int o = (by + ay[ti]) * WW + bx + ax[ti];
      if (quad >= 2) {
        f16x4 zz = {};
        *(f16x4*)(oz + (size_t)o * 32 + 16 + cbase) = zz;
      }
    }
  }
}

// ---------------------------------------------------------------------------
// Attention + fused Q, R19: 8x8 px tile -> 1024 blocks = 4 blocks/CU (was
// 512 = 2/CU, grid-limited) and 4-way split softmax: wave-uniform quarter
// h = tid>>6 handles ~13 of 49 positions per pixel; 4-way LDS merge
// (generalizes the proven 2-way merge). Halo 14x14 = 196 slots x 56 f16.
// ---------------------------------------------------------------------------
__global__ __launch_bounds__(256, 4) void attn_q(
    const f16* __restrict__ ABh, const f16* __restrict__ BF,
    const float* __restrict__ qw, const float* __restrict__ qb,
    const float* __restrict__ kb, const float* __restrict__ vb,
    float* __restrict__ out) {
  extern __shared__ char smem[];
  f16* kv = (f16*)smem;                        // 196 slots * 56 f16 = 21952 B
  f16* Wq = (f16*)(smem + 21952);              // 576 f16
  float* Qbv = (float*)(smem + 21952 + 1152);  // 24 f32
  const int tid = threadIdx.x;
  const int lane = tid & 63, wave = tid >> 6;
  const int n = lane & 15, quad = lane >> 4;
  const int cbase = quad * 4;
  const int bxA = ((int)blockIdx.x & 31) * 8, byA = ((int)blockIdx.x >> 5) * 8;

  for (int i = tid; i < 576; i += 256) Wq[i] = (f16)qw[i];
  if (tid < 24) Qbv[tid] = qb[tid];

  // ---- stage a-halo: 14x14 px, 4 x b128 chunks per px
  for (int idx = tid; idx < 784; idx += 256) {
    int slot = idx >> 2, c = idx & 3;
    int row = slot / 14, pxl = slot - row * 14;
    int gy = byA + row - 3, gx = bxA + pxl - 3;
    f16x8 v = {};
    if (gy >= 0 && gy < HH && gx >= 0 && gx < WW)
      v = *(const f16x8*)(ABh + ((size_t)(gy * WW + gx)) * 32 + c * 8);
    *(f16x8*)(kv + slot * 56 + c * 8) = v;
  }
  __syncthreads();

  const int px = tid & 63, h = tid >> 6;  // h is wave-uniform
  const int yl = px >> 3, xl = px & 7;
  const int pg = (byA + yl) * WW + bxA + xl;

  // snapshot own-center a before in-place overwrite
  const f16* cs = kv + ((yl + 3) * 14 + (xl + 3)) * 56;
  f16x8 a0 = *(const f16x8*)(cs);
  f16x8 a1 = *(const f16x8*)(cs + 8);
  f16x8 a2 = *(const f16x8*)(cs + 16);

  // b + fused Q (all 4 quarters compute; redundancy is cheap VALU)
  const f16* bhp = ABh + (size_t)NN * 32 + (size_t)pg * 32;
  f16x8 bb0 = *(const f16x8*)(bhp);
  f16x8 bb1 = *(const f16x8*)(bhp + 8);
  f16x8 bb2 = *(const f16x8*)(bhp + 16);
  float qf[24];
#pragma unroll
  for (int co = 0; co < 24; ++co) {
    float acc = Qbv[co];
    acc = dot8p(bb0, *(const f16x8*)(Wq + co * 24), acc);
    acc = dot8p(bb1, *(const f16x8*)(Wq + co * 24 + 8), acc);
    acc = dot8p(bb2, *(const f16x8*)(Wq + co * 24 + 16), acc);
    qf[co] = acc;
  }
  f16x8 q0, q1, q2;
#pragma unroll
  for (int c = 0; c < 8; ++c) {
    q0[c] = (f16)qf[c];
    q1[c] = (f16)qf[8 + c];
    q2[c] = (f16)qf[16 + c];
  }
  __syncthreads();  // snapshots + q done before in-place overwrite

  // ---- in-place K/V via swapped MFMA: 13 tiles x 16 slots (196 valid)
  {
    f16x8 KF[2], VF[2];
#pragma unroll
    for (int nt = 0; nt < 2; ++nt) {
      KF[nt] = *(const f16x8*)(BF + OQ + 1024 + (nt * 64 + lane) * 8);
      VF[nt] = *(const f16x8*)(BF + OQ + 2048 + (nt * 64 + lane) * 8);
    }
    float4 kb4[2], vb4[2];
#pragma unroll
    for (int nt = 0; nt < 2; ++nt) {
      int cc0 = nt * 16 + cbase;
      kb4[nt] = (cc0 < 24) ? *(const float4*)(kb + cc0)
                           : make_float4(0.f, 0.f, 0.f, 0.f);
      vb4[nt] = (cc0 < 24) ? *(const float4*)(vb + cc0)
                           : make_float4(0.f, 0.f, 0.f, 0.f);
    }
    for (int t = wave; t < 13; t += 4) {
      int qa = t * 16 + n;
      int qc = (qa > 195) ? 195 : qa;
      f16x8 a8 = *(const f16x8*)(kv + qc * 56 + quad * 8);
      f16x4 hk[2], hv[2];
#pragma unroll
      for (int nt = 0; nt < 2; ++nt) {
        f32x4 ak = {kb4[nt].x, kb4[nt].y, kb4[nt].z, kb4[nt].w};
        f32x4 av = {vb4[nt].x, vb4[nt].y, vb4[nt].z, vb4[nt].w};
        ak = __builtin_amdgcn_mfma_f32_16x16x32_f16(KF[nt], a8, ak, 0, 0, 0);
        av = __builtin_amdgcn_mfma_f32_16x16x32_f16(VF[nt], a8, av, 0, 0, 0);
#pragma unroll
        for (int reg = 0; reg < 4; ++reg) {
          hk[nt][reg] = (f16)ak[reg];
          hv[nt][reg] = (f16)av[reg];
        }
      }
      if (qa < 196) {
        f16* slot = kv + qa * 56;
#pragma unroll
        for (int nt = 0; nt < 2; ++nt) {
          int cc0 = nt * 16 + cbase;
          if (cc0 < 24) {
            *(f16x4*)(slot + cc0) = hk[nt];       // K at f16 [0:24)
            *(f16x4*)(slot + 24 + cc0) = hv[nt];  // V at f16 [24:48)
          }
        }
      }
    }
  }
  __syncthreads();

  // ---- scores: quarter h handles positions h*13 .. h*13+12 (pp<49)
  float s[13];
  float m = -3e38f;
#pragma unroll
  for (int i = 0; i < 13; ++i) {
    int pp = h * 13 + i;
    if (pp < 49) {
      int dy = pp / 7, dx = pp - (pp / 7) * 7;
      const f16* base = kv + ((yl + dy) * 14 + (xl + dx)) * 56;
      f16x8 k0 = *(const f16x8*)(base);
      f16x8 k1 = *(const f16x8*)(base + 8);
      f16x8 k2 = *(const f16x8*)(base + 16);
      float d = 0.f;
      d = dot8p(q0, k0, d);
      d = dot8p(q1, k1, d);
      d = dot8p(q2, k2, d);
      s[i] = d * 0.20412414523193154f;  // 1/sqrt(24)
      m = fmaxf(m, s[i]);
    } else {
      s[i] = -3e38f;
    }
  }
  float den = 0.f;
#pragma unroll
  for (int i = 0; i < 13; ++i) {
    float e = __expf(s[i] - m);
    s[i] = e;
    den += e;
  }

  // ---- un-normalized PV (f16 accum)
  f16x8 y0 = {}, y1 = {}, y2 = {};
#pragma unroll
  for (int i = 0; i < 13; ++i) {
    int pp = h * 13 + i;
    if (pp < 49) {
      int dy = pp / 7, dx = pp - (pp / 7) * 7;
      const f16* base = kv + ((yl + dy) * 14 + (xl + dx)) * 56 + 24;
      f16 wh = (f16)s[i];
      f16x8 w8 = {wh, wh, wh, wh, wh, wh, wh, wh};
      f16x8 v0 = *(const f16x8*)(base);
      f16x8 v1 = *(const f16x8*)(base + 8);
      f16x8 v2 = *(const f16x8*)(base + 16);
      y0 = v0 * w8 + y0;
      y1 = v1 * w8 + y1;
      y2 = v2 * w8 + y2;
    }
  }
  __syncthreads();  // all kv reads done -> reuse as exchange

  // ---- 4-way merge: quarters 1..3 publish partials (64 B/thread)
  if (h != 0) {
    f16* ex = kv + tid * 32;
    *(f16x8*)(ex) = y0;
    *(f16x8*)(ex + 8) = y1;
    *(f16x8*)(ex + 16) = y2;
    float* mf = (float*)(ex + 24);
    mf[0] = m;
    mf[1] = den;
  }
  __syncthreads();

  if (h == 0) {
    f16x8 p0[3], p1[3], p2[3];
    float mm[3], dd[3];
    float M = m;
#pragma unroll
    for (int hh = 0; hh < 3; ++hh) {
      const f16* ex = kv + ((hh + 1) * 64 + px) * 32;
      p0[hh] = *(const f16x8*)(ex);
      p1[hh] = *(const f16x8*)(ex + 8);
      p2[hh] = *(const f16x8*)(ex + 16);
      const float* mf = (const float*)(ex + 24);
      mm[hh] = mf[0];
      dd[hh] = mf[1];
      M = fmaxf(M, mm[hh]);
    }
    float f0 = __expf(m - M);
    float fh[3];
    float dtot = den * f0;
#pragma unroll
    for (int hh = 0; hh < 3; ++hh) {
      fh[hh] = __expf(mm[hh] - M);
      dtot += dd[hh] * fh[hh];
    }
    const float inv = 1.f / dtot;
#pragma unroll
    for (int c = 0; c < 8; ++c) {
      float v0 = (float)y0[c] * f0;
      float v1 = (float)y1[c] * f0;
      float v2 = (float)y2[c] * f0;
#pragma unroll
      for (int hh = 0; hh < 3; ++hh) {
        v0 += (float)p0[hh][c] * fh[hh];
        v1 += (float)p1[hh][c] * fh[hh];
        v2 += (float)p2[hh][c] * fh[hh];
      }
      out[(size_t)c * NN + pg] = v0 * inv + (float)a0[c];
      out[(size_t)(8 + c) * NN + pg] = v1 * inv + (float)a1[c];
      out[(size_t)(16 + c) * NN + pg] = v2 * inv + (float)a2[c];
    }
  } else if (h == 1) {
#pragma unroll
    for (int c = 0; c < 8; ++c) {
      out[(size_t)(24 + c) * NN + pg] = (float)bb0[c];
      out[(size_t)(32 + c) * NN + pg] = (float)bb1[c];
      out[(size_t)(40 + c) * NN + pg] = (float)bb2[c];
    }
  }
}

// ---------------------------------------------------------------------------
extern "C" void kernel_launch(void* const* d_in, const int* in_sizes, int n_in,
                              void* d_out, int out_size, void* d_ws,
                              size_t ws_size, hipStream_t stream) {
  const float* x = (const float*)d_in[0];
  const float* w0 = (const float*)d_in[1];
  const float* b0 = (const float*)d_in[2];
  const float* w1 = (const float*)d_in[3];
  const float* b1 = (const float*)d_in[4];
  const float* w2 = (const float*)d_in[5];
  const float* b2 = (const float*)d_in[6];
  const float* w3 = (const float*)d_in[7];
  const float* b3 = (const float*)d_in[8];
  const float* sw = (const float*)d_in[9];
  const float* sb = (const float*)d_in[10];
  const float* qw = (const float*)d_in[11];
  const float* qb = (const float*)d_in[12];
  const float* kw = (const float*)d_in[13];
  const float* kb = (const float*)d_in[14];
  const float* vw = (const float*)d_in[15];
  const float* vb = (const float*)d_in[16];
  float* out = (float*)d_out;

  f16* base = (f16*)d_ws;
  f16* ABh = base;                   // 2*NN*32 f16
  f16* BF = base + (size_t)64 * NN;  // 78336 f16

  prep<<<dim3(306), dim3(256), 0, stream>>>(w0, w1, w2, w3, qw, kw, vw, BF);
  fused_conv<<<dim3(1024), dim3(256), 61440, stream>>>(x, b0, b1, b2, b3, sw,
                                                       sb, ABh, BF);
  attn_q<<<dim3(1024), dim3(256), 23200, stream>>>(ABh, BF, qw, qb, kb, vb,
                                                   out);
}

// Round 20
// 151.068 us; speedup vs baseline: 1.1068x; 1.1068x over previous
//
#include <hip/hip_runtime.h>
#include <math.h>

#define HH 256
#define WW 256
#define NN (HH * WW)

typedef _Float16 f16;
typedef _Float16 f16x4 __attribute__((ext_vector_type(4)));
typedef _Float16 f16x8 __attribute__((ext_vector_type(8)));
typedef float f32x4 __attribute__((ext_vector_type(4)));

#define OQ 75264  // qkv B-frag base inside BF (f16 units)
#define CS 56     // conv LDS slot stride in f16 (R14/R18 proven)
#define IS 40     // im2col row stride in f16

__device__ inline float dot8p(f16x8 a, f16x8 b, float acc) {
#if __has_builtin(__builtin_amdgcn_fdot2)
  acc = __builtin_amdgcn_fdot2(__builtin_shufflevector(a, a, 0, 1),
                               __builtin_shufflevector(b, b, 0, 1), acc, false);
  acc = __builtin_amdgcn_fdot2(__builtin_shufflevector(a, a, 2, 3),
                               __builtin_shufflevector(b, b, 2, 3), acc, false);
  acc = __builtin_amdgcn_fdot2(__builtin_shufflevector(a, a, 4, 5),
                               __builtin_shufflevector(b, b, 4, 5), acc, false);
  acc = __builtin_amdgcn_fdot2(__builtin_shufflevector(a, a, 6, 7),
                               __builtin_shufflevector(b, b, 6, 7), acc, false);
  return acc;
#else
#pragma unroll
  for (int i = 0; i < 8; ++i) acc += (float)a[i] * (float)b[i];
  return acc;
#endif
}

// ---------------------------------------------------------------------------
// Weight repack element e -> BF[e]. co on lane&15, ci(k) on quad*8+j —
// valid as both MFMA B-frag and A-frag image (operand swap needs no change).
// ---------------------------------------------------------------------------
__device__ __forceinline__ float repack_elem(
    int e, const float* __restrict__ w0, const float* __restrict__ w1,
    const float* __restrict__ w2, const float* __restrict__ w3,
    const float* __restrict__ qw, const float* __restrict__ kw,
    const float* __restrict__ vw) {
  const int O1 = 1536, O2 = O1 + 27648, O3 = O2 + 27648;
  float val = 0.f;
  if (e >= OQ) {
    int idx = e - OQ;
    int mat = idx >> 10;
    int r = idx & 1023;
    int nt = r >> 9;
    int ln = (r >> 3) & 63;
    int j = r & 7;
    int nn = ln & 15, qd = ln >> 4;
    int ci = qd * 8 + j, co = nt * 16 + nn;
    const float* w = (mat == 0) ? qw : (mat == 1) ? kw : vw;
    if (ci < 24 && co < 24) val = w[co * 24 + ci];
  } else if (e < O1) {
    int j = e & 7;
    int ln = (e >> 3) & 63;
    int nt = e >> 9;
    int nn = ln & 15, qd = ln >> 4;
    int k = qd * 8 + j;
    int cout = nt * 16 + nn;
    if (k < 27) {
      int tap = k / 3, ci = k - tap * 3;
      val = w0[(cout * 3 + ci) * 9 + tap];
    }
  } else {
    const float* w;
    int COUT, idx;
    if (e < O2)      { w = w1; COUT = 48; idx = e - O1; }
    else if (e < O3) { w = w2; COUT = 48; idx = e - O2; }
    else             { w = w3; COUT = 24; idx = e - O3; }
    const int NT = (COUT == 48) ? 3 : 2;
    int j = idx & 7;
    int ln = (idx >> 3) & 63;
    int rest = idx >> 9;
    int nt = rest % NT;
    int q2 = rest / NT;
    int kc = q2 & 1;
    int tap = q2 >> 1;
    int nn = ln & 15, qd = ln >> 4;
    int ci = kc * 32 + qd * 8 + j;
    int cout = nt * 16 + nn;
    if (ci < 48 && cout < COUT) val = w[(cout * 48 + ci) * 9 + tap];
  }
  return val;
}

__global__ __launch_bounds__(256) void prep(
    const float* __restrict__ w0, const float* __restrict__ w1,
    const float* __restrict__ w2, const float* __restrict__ w3,
    const float* __restrict__ qw, const float* __restrict__ kw,
    const float* __restrict__ vw, f16* __restrict__ bf) {
  int e = blockIdx.x * 256 + threadIdx.x;  // 306*256 = 78336 exactly
  bf[e] = (f16)repack_elem(e, w0, w1, w2, w3, qw, kw, vw);
}

// ---------------------------------------------------------------------------
// Middle conv stage (48->48), LDS->LDS, operand-swapped MFMA (weights=A,
// activations=B). Byte-identical to R18 (best measured 51.4 µs).
// ---------------------------------------------------------------------------
template <int W_IN, int W_OUT, int H_OUT, int MAXT>
__device__ __forceinline__ void stage_mid(const f16* __restrict__ inb,
                                          f16* __restrict__ outb,
                                          const f16* __restrict__ bfr,
                                          const float* __restrict__ bias,
                                          int gy0, int gx0, int tid) {
  const int P = W_OUT * H_OUT;
  const int T = (P + 15) >> 4;
  const int lane = tid & 63, wave = tid >> 6;
  const int n = lane & 15, quad = lane >> 4;
  const int cbase = quad * 4;
  f32x4 acc[MAXT][3];
  int ay[MAXT], ax[MAXT];
  float4 bv[3];
#pragma unroll
  for (int nt = 0; nt < 3; ++nt)
    bv[nt] = *(const float4*)(bias + nt * 16 + cbase);
#pragma unroll
  for (int ti = 0; ti < MAXT; ++ti) {
    int qa = (wave + 4 * ti) * 16 + n;
    int qc = (qa > P - 1) ? (P - 1) : qa;
    ay[ti] = qc / W_OUT;
    ax[ti] = qc - ay[ti] * W_OUT;
#pragma unroll
    for (int nt = 0; nt < 3; ++nt)
      acc[ti][nt] = (f32x4){bv[nt].x, bv[nt].y, bv[nt].z, bv[nt].w};
  }
#pragma unroll 1
  for (int tap = 0; tap < 9; ++tap) {
    const int dy = tap / 3, dx = tap - dy * 3;
    f16x8 B[2][3];
#pragma unroll
    for (int kc = 0; kc < 2; ++kc)
#pragma unroll
      for (int nt = 0; nt < 3; ++nt)
        B[kc][nt] =
            *(const f16x8*)(bfr + (((tap * 2 + kc) * 3 + nt) * 64 + lane) * 8);
#pragma unroll
    for (int ti = 0; ti < MAXT; ++ti) {
      if (wave + 4 * ti < T) {
        const f16* ap = inb + ((ay[ti] + dy) * W_IN + ax[ti] + dx) * CS +
                        quad * 8;
        f16x8 a0 = *(const f16x8*)(ap);
        f16x8 a1 = *(const f16x8*)(ap + 32);
#pragma unroll
        for (int nt = 0; nt < 3; ++nt)
          acc[ti][nt] = __builtin_amdgcn_mfma_f32_16x16x32_f16(
              B[0][nt], a0, acc[ti][nt], 0, 0, 0);
#pragma unroll
        for (int nt = 0; nt < 3; ++nt)
          acc[ti][nt] = __builtin_amdgcn_mfma_f32_16x16x32_f16(
              B[1][nt], a1, acc[ti][nt], 0, 0, 0);
      }
    }
  }
#pragma unroll
  for (int ti = 0; ti < MAXT; ++ti) {
    int qa = (wave + 4 * ti) * 16 + n;
    if (wave + 4 * ti < T && qa < P) {
      int gy = gy0 + ay[ti], gx = gx0 + ax[ti];
      bool im = (gy >= 0 && gy < HH && gx >= 0 && gx < WW);
#pragma unroll
      for (int nt = 0; nt < 3; ++nt) {
        f16x4 h;
#pragma unroll
        for (int reg = 0; reg < 4; ++reg)
          h[reg] = (f16)(im ? fmaxf(acc[ti][nt][reg], 0.f) : 0.f);
        *(f16x4*)(outb + qa * CS + nt * 16 + cbase) = h;
      }
    }
  }
}

// ---------------------------------------------------------------------------
// FUSED CONV CHAIN — byte-identical to R18 (best measured: 51.4 µs).
// ---------------------------------------------------------------------------
__global__ __launch_bounds__(256, 2) void fused_conv(
    const float* __restrict__ x, const float* __restrict__ b0,
    const float* __restrict__ b1, const float* __restrict__ b2,
    const float* __restrict__ b3, const float* __restrict__ sw,
    const float* __restrict__ sb, f16* __restrict__ ABh,
    const f16* __restrict__ BF) {
  extern __shared__ char smem[];
  f16* bufA = (f16*)smem;
  f16* bufB = (f16*)(smem + 34496);
  const int tid = threadIdx.x;
  const int bz = blockIdx.x;
  const int z = bz >> 9, tt = bz & 511;
  const int bx = (tt & 15) * 16, by = (tt >> 4) * 8;
  const int lane = tid & 63, wave = tid >> 6;
  const int n = lane & 15, quad = lane >> 4;
  const int cbase = quad * 4;
  const float* xz = x + (size_t)z * 3 * NN;

  f16x8 B0[3];
#pragma unroll
  for (int nt = 0; nt < 3; ++nt)
    B0[nt] = *(const f16x8*)(BF + (nt * 64 + lane) * 8);

  for (int i = tid; i < 3840; i += 256) {  // 61440 B
    f16x8 zz = {};
    *(f16x8*)(smem + i * 16) = zz;
  }
  __syncthreads();

  for (int p = tid; p < 308; p += 256) {
    int py = p / 22, px = p - py * 22;
    int gy = by - 3 + py, gx = bx - 3 + px;
    f16 row[32];
#pragma unroll
    for (int k = 27; k < 32; ++k) row[k] = (f16)0.f;
#pragma unroll
    for (int tap = 0; tap < 9; ++tap) {
      int dy = tap / 3, dx = tap - (tap / 3) * 3;
      int sy = gy + dy - 1, sx = gx + dx - 1;
      f16 c0 = (f16)0.f, c1 = c0, c2 = c0;
      if (sy >= 0 && sy < HH && sx >= 0 && sx < WW) {
        int o = sy * WW + sx;
        c0 = (f16)xz[o];
        c1 = (f16)xz[NN + o];
        c2 = (f16)xz[2 * NN + o];
      }
      row[tap * 3 + 0] = c0;
      row[tap * 3 + 1] = c1;
      row[tap * 3 + 2] = c2;
    }
    f16* dst = bufB + p * IS;
#pragma unroll
    for (int c = 0; c < 4; ++c)
      *(f16x8*)(dst + c * 8) = *(f16x8*)(row + c * 8);
  }
  __syncthreads();

  {
    float4 bv[3];
#pragma unroll
    for (int nt = 0; nt < 3; ++nt)
      bv[nt] = *(const float4*)(b0 + nt * 16 + cbase);
    f32x4 acc[5][3];
    int pya[5], pxa[5];
#pragma unroll
    for (int ti = 0; ti < 5; ++ti) {
      int qa = (wave + 4 * ti) * 16 + n;
      int qc = (qa > 307) ? 307 : qa;
      pya[ti] = qc / 22;
      pxa[ti] = qc - pya[ti] * 22;
#pragma unroll
      for (int nt = 0; nt < 3; ++nt)
        acc[ti][nt] = (f32x4){bv[nt].x, bv[nt].y, bv[nt].z, bv[nt].w};
    }
#pragma unroll
    for (int ti = 0; ti < 5; ++ti) {
      int qa = (wave + 4 * ti) * 16 + n;
      int qc = (qa > 307) ? 307 : qa;
      f16x8 a = *(const f16x8*)(bufB + qc * IS + quad * 8);
#pragma unroll
      for (int nt = 0; nt < 3; ++nt)
        acc[ti][nt] = __builtin_amdgcn_mfma_f32_16x16x32_f16(B0[nt], a,
                                                             acc[ti][nt], 0,
                                                             0, 0);
    }
    __syncthreads();
#pragma unroll
    for (int ti = 0; ti < 5; ++ti) {
      int qa = (wave + 4 * ti) * 16 + n;
      if (qa < 308) {
        int gy = by - 3 + pya[ti], gx = bx - 3 + pxa[ti];
        bool im = (gy >= 0 && gy < HH && gx >= 0 && gx < WW);
#pragma unroll
        for (int nt = 0; nt < 3; ++nt) {
          f16x4 h;
#pragma unroll
          for (int reg = 0; reg < 4; ++reg)
            h[reg] = (f16)(im ? fmaxf(acc[ti][nt][reg], 0.f) : 0.f);
          *(f16x4*)(bufA + qa * CS + nt * 16 + cbase) = h;
        }
      }
    }
  }
  __syncthreads();

  stage_mid<22, 20, 12, 4>(bufA, bufB, BF + 1536, b1, by - 2, bx - 2, tid);
  __syncthreads();
  stage_mid<20, 18, 10, 3>(bufB, bufA, BF + 29184, b2, by - 1, bx - 1, tid);
  __syncthreads();

  {
    f32x4 acc[2][2];
    int ay[2], ax[2];
    float skw0[2][4], skw1[2][4], skw2[2][4], skb4[2][4];
#pragma unroll
    for (int nt = 0; nt < 2; ++nt)
#pragma unroll
      for (int reg = 0; reg < 4; ++reg) {
        int cc = nt * 16 + cbase + reg;
        bool v = (cc < 24);
        skw0[nt][reg] = v ? sw[cc * 3 + 0] : 0.f;
        skw1[nt][reg] = v ? sw[cc * 3 + 1] : 0.f;
        skw2[nt][reg] = v ? sw[cc * 3 + 2] : 0.f;
        skb4[nt][reg] = v ? sb[cc] : 0.f;
      }
#pragma unroll
    for (int ti = 0; ti < 2; ++ti) {
      int qa = (wave + 4 * ti) * 16 + n;
      ay[ti] = qa >> 4;
      ax[ti] = qa & 15;
#pragma unroll
      for (int nt = 0; nt < 2; ++nt) {
        int cc0 = nt * 16 + cbase;
        float4 bv = (cc0 < 24) ? *(const float4*)(b3 + cc0)
                               : make_float4(0.f, 0.f, 0.f, 0.f);
        acc[ti][nt] = (f32x4){bv.x, bv.y, bv.z, bv.w};
      }
    }
#pragma unroll 1
    for (int tap = 0; tap < 9; ++tap) {
      const int dy = tap / 3, dx = tap - dy * 3;
      f16x8 B[2][2];
#pragma unroll
      for (int kc = 0; kc < 2; ++kc)
#pragma unroll
        for (int nt = 0; nt < 2; ++nt)
          B[kc][nt] = *(const f16x8*)(BF + 56832 +
                                      (((tap * 2 + kc) * 2 + nt) * 64 + lane) *
                                          8);
#pragma unroll
      for (int ti = 0; ti < 2; ++ti) {
        const f16* ap = bufA + ((ay[ti] + dy) * 18 + ax[ti] + dx) * CS +
                        quad * 8;
        f16x8 a0 = *(const f16x8*)(ap);
        f16x8 a1 = *(const f16x8*)(ap + 32);
#pragma unroll
        for (int nt = 0; nt < 2; ++nt)
          acc[ti][nt] = __builtin_amdgcn_mfma_f32_16x16x32_f16(
              B[0][nt], a0, acc[ti][nt], 0, 0, 0);
#pragma unroll
        for (int nt = 0; nt < 2; ++nt)
          acc[ti][nt] = __builtin_amdgcn_mfma_f32_16x16x32_f16(
              B[1][nt], a1, acc[ti][nt], 0, 0, 0);
      }
    }
    f16* oz = ABh + (size_t)z * NN * 32;
#pragma unroll
    for (int ti = 0; ti < 2; ++ti) {
      int o = (by + ay[ti]) * WW + bx + ax[ti];
      float xv0 = xz[o], xv1 = xz[NN + o], xv2 = xz[2 * NN + o];
#pragma unroll
      for (int nt = 0; nt < 2; ++nt) {
        int cc0 = nt * 16 + cbase;
        if (cc0 < 24) {
          f16x4 h;
#pragma unroll
          for (int reg = 0; reg < 4; ++reg) {
            float sk = skb4[nt][reg] + skw0[nt][reg] * xv0 +
                       skw1[nt][reg] * xv1 + skw2[nt][reg] * xv2;
            h[reg] = (f16)(fmaxf(acc[ti][nt][reg], 0.f) + sk);
          }
          *(f16x4*)(oz + (size_t)o * 32 + cc0) = h;
        }
      }
    }
#pragma unroll
    for (int ti = 0; ti < 2; ++ti) {
      int o = (by + ay[ti]) * WW + bx + ax[ti];
      if (quad >= 2) {
        f16x4 zz = {};
        *(f16x4*)(oz + (size_t)o * 32 + 16 + cbase) = zz;
      }
    }
  }
}

// ---------------------------------------------------------------------------
// Attention + fused Q — byte-identical to the R18 passing version (16x8
// tile, 2-way split softmax; R19's 8x8/4-way retile regressed and is
// reverted).
// ---------------------------------------------------------------------------
__global__ __launch_bounds__(256, 3) void attn_q(
    const f16* __restrict__ ABh, const f16* __restrict__ BF,
    const float* __restrict__ qw, const float* __restrict__ qb,
    const float* __restrict__ kb, const float* __restrict__ vb,
    float* __restrict__ out) {
  extern __shared__ char smem[];
  f16* kv = (f16*)smem;                        // 320 slots * 56 f16
  f16* Wq = (f16*)(smem + 35840);              // 576 f16
  float* Qbv = (float*)(smem + 35840 + 1152);  // 24 f32
  const int tid = threadIdx.x;
  const int lane = tid & 63, wave = tid >> 6;
  const int n = lane & 15, quad = lane >> 4;
  const int cbase = quad * 4;
  const int bxA = ((int)blockIdx.x & 15) * 16, byA = ((int)blockIdx.x >> 4) * 8;

  for (int i = tid; i < 576; i += 256) Wq[i] = (f16)qw[i];
  if (tid < 24) Qbv[tid] = qb[tid];

  for (int idx = tid; idx < 1232; idx += 256) {
    int slot = idx >> 2, c = idx & 3;
    int row = slot / 22, pxl = slot - row * 22;
    int gy = byA + row - 3, gx = bxA + pxl - 3;
    f16x8 v = {};
    if (gy >= 0 && gy < HH && gx >= 0 && gx < WW)
      v = *(const f16x8*)(ABh + ((size_t)(gy * WW + gx)) * 32 + c * 8);
    *(f16x8*)(kv + slot * 56 + c * 8) = v;
  }
  __syncthreads();

  const int t7 = tid & 127, half = tid >> 7;  // wave-uniform half
  const int yl = t7 >> 4, xl = t7 & 15;
  const int pg = (byA + yl) * WW + bxA + xl;

  const f16* cs = kv + ((yl + 3) * 22 + (xl + 3)) * 56;
  f16x8 a0 = *(const f16x8*)(cs);
  f16x8 a1 = *(const f16x8*)(cs + 8);
  f16x8 a2 = *(const f16x8*)(cs + 16);

  const f16* bhp = ABh + (size_t)NN * 32 + (size_t)pg * 32;
  f16x8 bb0 = *(const f16x8*)(bhp);
  f16x8 bb1 = *(const f16x8*)(bhp + 8);
  f16x8 bb2 = *(const f16x8*)(bhp + 16);
  float qf[24];
#pragma unroll
  for (int co = 0; co < 24; ++co) {
    float acc = Qbv[co];
    acc = dot8p(bb0, *(const f16x8*)(Wq + co * 24), acc);
    acc = dot8p(bb1, *(const f16x8*)(Wq + co * 24 + 8), acc);
    acc = dot8p(bb2, *(const f16x8*)(Wq + co * 24 + 16), acc);
    qf[co] = acc;
  }
  f16x8 q0, q1, q2;
#pragma unroll
  for (int c = 0; c < 8; ++c) {
    q0[c] = (f16)qf[c];
    q1[c] = (f16)qf[8 + c];
    q2[c] = (f16)qf[16 + c];
  }
  __syncthreads();  // snapshots + q done before in-place overwrite

  {
    f16x8 KF[2], VF[2];
#pragma unroll
    for (int nt = 0; nt < 2; ++nt) {
      KF[nt] = *(const f16x8*)(BF + OQ + 1024 + (nt * 64 + lane) * 8);
      VF[nt] = *(const f16x8*)(BF + OQ + 2048 + (nt * 64 + lane) * 8);
    }
    float4 kb4[2], vb4[2];
#pragma unroll
    for (int nt = 0; nt < 2; ++nt) {
      int cc0 = nt * 16 + cbase;
      kb4[nt] = (cc0 < 24) ? *(const float4*)(kb + cc0)
                           : make_float4(0.f, 0.f, 0.f, 0.f);
      vb4[nt] = (cc0 < 24) ? *(const float4*)(vb + cc0)
                           : make_float4(0.f, 0.f, 0.f, 0.f);
    }
    for (int t = wave; t < 20; t += 4) {
      f16x8 a8 = *(const f16x8*)(kv + (t * 16 + n) * 56 + quad * 8);
      f16x4 hk[2], hv[2];
#pragma unroll
      for (int nt = 0; nt < 2; ++nt) {
        f32x4 ak = {kb4[nt].x, kb4[nt].y, kb4[nt].z, kb4[nt].w};
        f32x4 av = {vb4[nt].x, vb4[nt].y, vb4[nt].z, vb4[nt].w};
        ak = __builtin_amdgcn_mfma_f32_16x16x32_f16(KF[nt], a8, ak, 0, 0, 0);
        av = __builtin_amdgcn_mfma_f32_16x16x32_f16(VF[nt], a8, av, 0, 0, 0);
#pragma unroll
        for (int reg = 0; reg < 4; ++reg) {
          hk[nt][reg] = (f16)ak[reg];
          hv[nt][reg] = (f16)av[reg];
        }
      }
      f16* slot = kv + (t * 16 + n) * 56;
#pragma unroll
      for (int nt = 0; nt < 2; ++nt) {
        int cc0 = nt * 16 + cbase;
        if (cc0 < 24) {
          *(f16x4*)(slot + cc0) = hk[nt];       // K at f16 [0:24)
          *(f16x4*)(slot + 24 + cc0) = hv[nt];  // V at f16 [24:48)
        }
      }
    }
  }
  __syncthreads();

  float s[25];
  float m = -3e38f;
#pragma unroll
  for (int i = 0; i < 25; ++i) {
    int pp = half * 25 + i;
    if (pp < 49) {
      int dy = pp / 7, dx = pp - (pp / 7) * 7;
      const f16* base = kv + ((yl + dy) * 22 + (xl + dx)) * 56;
      f16x8 k0 = *(const f16x8*)(base);
      f16x8 k1 = *(const f16x8*)(base + 8);
      f16x8 k2 = *(const f16x8*)(base + 16);
      float d = 0.f;
      d = dot8p(q0, k0, d);
      d = dot8p(q1, k1, d);
      d = dot8p(q2, k2, d);
      s[i] = d * 0.20412414523193154f;  // 1/sqrt(24)
      m = fmaxf(m, s[i]);
    } else {
      s[i] = -3e38f;
    }
  }
  float den = 0.f;
#pragma unroll
  for (int i = 0; i < 25; ++i) {
    float e = __expf(s[i] - m);
    s[i] = e;
    den += e;
  }

  f16x8 y0 = {}, y1 = {}, y2 = {};
#pragma unroll
  for (int i = 0; i < 25; ++i) {
    int pp = half * 25 + i;
    if (pp < 49) {
      int dy = pp / 7, dx = pp - (pp / 7) * 7;
      const f16* base = kv + ((yl + dy) * 22 + (xl + dx)) * 56 + 24;
      f16 wh = (f16)s[i];
      f16x8 w8 = {wh, wh, wh, wh, wh, wh, wh, wh};
      f16x8 v0 = *(const f16x8*)(base);
      f16x8 v1 = *(const f16x8*)(base + 8);
      f16x8 v2 = *(const f16x8*)(base + 16);
      y0 = v0 * w8 + y0;
      y1 = v1 * w8 + y1;
      y2 = v2 * w8 + y2;
    }
  }
  __syncthreads();  // kv reads done -> reuse as exchange

  if (half == 1) {
    f16* ex = kv + t7 * 56;
    *(f16x8*)(ex) = y0;
    *(f16x8*)(ex + 8) = y1;
    *(f16x8*)(ex + 16) = y2;
    float* mf = (float*)(ex + 24);
    mf[0] = m;
    mf[1] = den;
  }
  __syncthreads();

  if (half == 0) {
    const f16* ex = kv + t7 * 56;
    f16x8 yb0 = *(const f16x8*)(ex);
    f16x8 yb1 = *(const f16x8*)(ex + 8);
    f16x8 yb2 = *(const f16x8*)(ex + 16);
    const float* mf = (const float*)(ex + 24);
    float mB = mf[0], dB = mf[1];
    float M = fmaxf(m, mB);
    float fa = __expf(m - M), fb = __expf(mB - M);
    float inv = 1.f / (den * fa + dB * fb);
#pragma unroll
    for (int c = 0; c < 8; ++c) {
      out[(size_t)c * NN + pg] =
          ((float)y0[c] * fa + (float)yb0[c] * fb) * inv + (float)a0[c];
      out[(size_t)(8 + c) * NN + pg] =
          ((float)y1[c] * fa + (float)yb1[c] * fb) * inv + (float)a1[c];
      out[(size_t)(16 + c) * NN + pg] =
          ((float)y2[c] * fa + (float)yb2[c] * fb) * inv + (float)a2[c];
    }
  } else {
#pragma unroll
    for (int c = 0; c < 8; ++c) {
      out[(size_t)(24 + c) * NN + pg] = (float)bb0[c];
      out[(size_t)(32 + c) * NN + pg] = (float)bb1[c];
      out[(size_t)(40 + c) * NN + pg] = (float)bb2[c];
    }
  }
}

// ---------------------------------------------------------------------------
extern "C" void kernel_launch(void* const* d_in, const int* in_sizes, int n_in,
                              void* d_out, int out_size, void* d_ws,
                              size_t ws_size, hipStream_t stream) {
  const float* x = (const float*)d_in[0];
  const float* w0 = (const float*)d_in[1];
  const float* b0 = (const float*)d_in[2];
  const float* w1 = (const float*)d_in[3];
  const float* b1 = (const float*)d_in[4];
  const float* w2 = (const float*)d_in[5];
  const float* b2 = (const float*)d_in[6];
  const float* w3 = (const float*)d_in[7];
  const float* b3 = (const float*)d_in[8];
  const float* sw = (const float*)d_in[9];
  const float* sb = (const float*)d_in[10];
  const float* qw = (const float*)d_in[11];
  const float* qb = (const float*)d_in[12];
  const float* kw = (const float*)d_in[13];
  const float* kb = (const float*)d_in[14];
  const float* vw = (const float*)d_in[15];
  const float* vb = (const float*)d_in[16];
  float* out = (float*)d_out;

  f16* base = (f16*)d_ws;
  f16* ABh = base;                   // 2*NN*32 f16
  f16* BF = base + (size_t)64 * NN;  // 78336 f16

  prep<<<dim3(306), dim3(256), 0, stream>>>(w0, w1, w2, w3, qw, kw, vw, BF);
  fused_conv<<<dim3(1024), dim3(256), 61440, stream>>>(x, b0, b1, b2, b3, sw,
                                                       sb, ABh, BF);
  attn_q<<<dim3(512), dim3(256), 37088, stream>>>(ABh, BF, qw, qb, kb, vb,
                                                  out);
}